// Round 11
// baseline (79.161 us; speedup 1.0000x reference)
//
#include <hip/hip_runtime.h>
#include <cmath>

constexpr int B_ = 2, H_ = 8, N_ = 2048, DK_ = 64, DV_ = 64;
constexpr int BH_ = B_ * H_;      // 16
constexpr int C_ = 64;            // chunk size
constexpr int NC_ = N_ / C_;      // 32 chunks per (b,h)
constexpr int NCH_ = BH_ * NC_;   // 512 chunks total

using f32x16 = __attribute__((ext_vector_type(16))) float;
using bf16x8 = __attribute__((ext_vector_type(8))) __bf16;

__device__ inline unsigned short bfr(float x) {
  unsigned u = __float_as_uint(x);
  return (unsigned short)((u + 0x7FFFu + ((u >> 16) & 1u)) >> 16);
}
__device__ inline unsigned pk2(float lo, float hi) {
  return (unsigned)bfr(lo) | ((unsigned)bfr(hi) << 16);
}
__device__ inline float bf2f(unsigned short s) {
  return __uint_as_float(((unsigned)s) << 16);
}
// swizzled ushort index into a [64][64] bf16 tile (row stride 128B)
__device__ inline int swi(int row, int a) {
  return (row * 128 + (((a * 2) ^ ((row & 7) << 4)))) >> 1;
}

// ---------------------------------------------------------------------------
// Kernel 1 (fused front): blocks 0..511  -> per-chunk sums (kc inline from
// omask[:,0]; k̄ staged f32 for EXACT ksum; v staged bf16 — numerator-only,
// same error class as the out kernel's vT). Blocks 512.. -> coef (round-1
// proven shape). LDS 24.8KB keeps 6 blocks/CU for the coef stream.
// ---------------------------------------------------------------------------
__global__ __launch_bounds__(256) void front_kernel(const float* __restrict__ kg,
                                                    const float* __restrict__ vg,
                                                    const float* __restrict__ om,
                                                    float* __restrict__ qc,
                                                    float* __restrict__ kc,
                                                    float* __restrict__ ksum,
                                                    float* __restrict__ kvsum) {
  __shared__ float kb[C_][DK_];              // 16 KB (f32 — feeds exact ksum)
  __shared__ unsigned short vsb[C_][DV_];    // 8 KB  (bf16 — numerator only)
  __shared__ float smkc[C_];
  int t = threadIdx.x;
  if (blockIdx.x < NCH_) {
    int chunk = blockIdx.x;
    int bh = chunk / NC_, ci = chunk - bh * NC_;
    int r0 = ci * C_;
    int rowb = bh * N_ + r0;
    size_t gbase = (size_t)rowb * DK_;
    if (t < 64) smkc[t] = 1.0f / om[(size_t)(rowb + t) * N_];
    __syncthreads();
#pragma unroll
    for (int p = 0; p < 4; ++p) {
      int f = t + p * 256;
      int row = f >> 4, col = (f & 15) * 4;
      float sc = smkc[row];
      float4 k4 = *(const float4*)(kg + gbase + (size_t)f * 4);
      k4.x *= sc; k4.y *= sc; k4.z *= sc; k4.w *= sc;
      *(float4*)&kb[row][col] = k4;
      float4 v4 = *(const float4*)(vg + gbase + (size_t)f * 4);
      vsb[row][col + 0] = bfr(v4.x); vsb[row][col + 1] = bfr(v4.y);
      vsb[row][col + 2] = bfr(v4.z); vsb[row][col + 3] = bfr(v4.w);
    }
    __syncthreads();
    int dk0 = (t & 15) * 4, dv0 = (t >> 4) * 4;
    float acc[4][4] = {};
    float ks[4] = {};
    for (int r = 0; r < C_; ++r) {
      float4 k4 = *(const float4*)&kb[r][dk0];
      ushort4 vu = *(const ushort4*)&vsb[r][dv0];
      float ka[4] = {k4.x, k4.y, k4.z, k4.w};
      float va[4] = {bf2f(vu.x), bf2f(vu.y), bf2f(vu.z), bf2f(vu.w)};
#pragma unroll
      for (int i = 0; i < 4; ++i) {
        ks[i] += ka[i];
#pragma unroll
        for (int j = 0; j < 4; ++j) acc[i][j] += ka[i] * va[j];
      }
    }
    float* kvc = kvsum + (size_t)chunk * (DK_ * DV_);
#pragma unroll
    for (int i = 0; i < 4; ++i)
      *(float4*)(kvc + (size_t)(dk0 + i) * DV_ + dv0) =
          make_float4(acc[i][0], acc[i][1], acc[i][2], acc[i][3]);
    if (t < 16) {
#pragma unroll
      for (int i = 0; i < 4; ++i) ksum[(size_t)chunk * DK_ + dk0 + i] = ks[i];
    }
  } else {
    int row = (blockIdx.x - NCH_) * 4 + (t >> 6);
    int lane = t & 63;
    const float* r = om + (size_t)row * N_;
    float s = 0.f;
#pragma unroll
    for (int kk = 0; kk < N_ / 256; ++kk) {
      float4 v4 = *(const float4*)(r + kk * 256 + lane * 4);
      s += (v4.x + v4.y) + (v4.z + v4.w);
    }
#pragma unroll
    for (int off = 32; off > 0; off >>= 1) s += __shfl_xor(s, off, 64);
    if (lane == 0) {
      float o0 = r[0];
      qc[row] = o0 / sqrtf(s);
      kc[row] = 1.0f / o0;
    }
  }
}

// ---------------------------------------------------------------------------
// Kernel 2: out (round-7 proven MFMA numerator + f32 P) with IN-BLOCK
// exclusive prefix over predecessor chunk sums (replaces the scan kernel).
// kv array = 8MB, L2/L3-resident; ~127MB of L2-hit reads across 512 blocks.
// ---------------------------------------------------------------------------
__global__ __launch_bounds__(256) void out_mfma_kernel(
    const float* __restrict__ qg, const float* __restrict__ kg,
    const float* __restrict__ vg, const float* __restrict__ qc,
    const float* __restrict__ kc, const float* __restrict__ ksum,
    const float* __restrict__ kvsum, float* __restrict__ outg) {
  __shared__ unsigned short qb[64 * 64];
  __shared__ unsigned short kb[64 * 64];
  __shared__ unsigned short sS[64 * 64];
  __shared__ unsigned short vT[64 * 64];
  __shared__ unsigned short dT[64 * 64];
  __shared__ float Tc[2][64][68];
  __shared__ float Tl[64];
  __shared__ float Pf[64];

  const int chunk = blockIdx.x;
  const int bh = chunk >> 5, ci = chunk & 31;
  const int r0 = ci * C_;
  const int rowb = bh * N_ + r0;
  const size_t gbase = (size_t)rowb * DK_;
  const int t = threadIdx.x;
  const int i = t >> 2, a0 = (t & 3) * 16;

  // ---- in-block exclusive prefix: D_pre (registers) + T_pre (Tl) ----
  float pre[16];
#pragma unroll
  for (int u = 0; u < 16; ++u) pre[u] = 0.f;
  {
    const float* kvb = kvsum + (size_t)(bh * NC_) * (DK_ * DV_)
                       + (size_t)i * 64 + a0;
    for (int cc = 0; cc < ci; ++cc) {
      const float* pp2 = kvb + (size_t)cc * (DK_ * DV_);
#pragma unroll
      for (int u4 = 0; u4 < 4; ++u4) {
        float4 x = *(const float4*)(pp2 + u4 * 4);
        pre[u4 * 4 + 0] += x.x; pre[u4 * 4 + 1] += x.y;
        pre[u4 * 4 + 2] += x.z; pre[u4 * 4 + 3] += x.w;
      }
    }
    if (t < 64) {
      float s = 0.f;
      const float* ksb = ksum + (size_t)(bh * NC_) * DK_ + t;
      for (int cc = 0; cc < ci; ++cc) s += ksb[(size_t)cc * DK_];
      Tl[t] = s;
    }
  }

  float xq[16];
  {
    float qcv = qc[rowb + i];
    float kcv = kc[rowb + i];
    float xk[16], xv[16];
    {
      const float* qp = qg + gbase + (size_t)i * 64 + a0;
      const float* kp = kg + gbase + (size_t)i * 64 + a0;
      const float* vp = vg + gbase + (size_t)i * 64 + a0;
#pragma unroll
      for (int u = 0; u < 4; ++u) {
        *(float4*)&xq[u * 4] = *(const float4*)(qp + u * 4);
        *(float4*)&xk[u * 4] = *(const float4*)(kp + u * 4);
        *(float4*)&xv[u * 4] = *(const float4*)(vp + u * 4);
      }
    }
#pragma unroll
    for (int u = 0; u < 16; ++u) { xq[u] *= qcv; xk[u] *= kcv; }
#pragma unroll
    for (int u4 = 0; u4 < 4; ++u4)
      *(float4*)&Tc[0][i][a0 + u4 * 4] = *(const float4*)&xk[u4 * 4];
    unsigned* qbu = (unsigned*)qb;
    unsigned* kbu = (unsigned*)kb;
#pragma unroll
    for (int u = 0; u < 8; ++u) {
      int a = a0 + 2 * u;
      int bi = (i * 128 + (((a * 2) ^ ((i & 7) << 4)))) >> 2;
      qbu[bi] = pk2(xq[2 * u], xq[2 * u + 1]);
      kbu[bi] = pk2(xk[2 * u], xk[2 * u + 1]);
    }
#pragma unroll
    for (int u = 0; u < 16; ++u) {
      int c = a0 + u;
      vT[swi(c, i)] = bfr(xv[u]);
      dT[swi(c, i)] = bfr(pre[u]);    // D_pre^T, bf16 (numerator only)
    }
  }
  __syncthreads();
  {
    int p = 0;
#pragma unroll
    for (int step = 1; step < 64; step <<= 1) {
      float4 cur[4], prv[4];
#pragma unroll
      for (int u4 = 0; u4 < 4; ++u4) {
        cur[u4] = *(const float4*)&Tc[p][i][a0 + u4 * 4];
        if (i >= step)
          prv[u4] = *(const float4*)&Tc[p][i - step][a0 + u4 * 4];
        else
          prv[u4] = make_float4(0.f, 0.f, 0.f, 0.f);
      }
#pragma unroll
      for (int u4 = 0; u4 < 4; ++u4) {
        float4 w = make_float4(cur[u4].x + prv[u4].x, cur[u4].y + prv[u4].y,
                               cur[u4].z + prv[u4].z, cur[u4].w + prv[u4].w);
        *(float4*)&Tc[p ^ 1][i][a0 + u4 * 4] = w;
      }
      __syncthreads();
      p ^= 1;
    }
  }
  {
    float part = 0.f;
#pragma unroll
    for (int u = 0; u < 16; ++u)
      part += xq[u] * (Tl[a0 + u] + Tc[0][i][a0 + u]);
    part += __shfl_xor(part, 1, 64);
    part += __shfl_xor(part, 2, 64);
    if ((t & 3) == 0) Pf[i] = 1.0f / fmaxf(fabsf(part), 1.0f);
  }
  const int lane = t & 63, w = t >> 6;
  const int wr = w >> 1, wc = w & 1;
  const int half = lane >> 5, col = lane & 31;
  const int arow = 32 * wr + col;
  const int bcol = 32 * wc + col;
  f32x16 accS;
#pragma unroll
  for (int r = 0; r < 16; ++r) accS[r] = 0.f;
#pragma unroll
  for (int kk = 0; kk < 4; ++kk) {
    int aa = kk * 16 + half * 8;
    bf16x8 af = *(const bf16x8*)&qb[swi(arow, aa)];
    bf16x8 bf = *(const bf16x8*)&kb[swi(bcol, aa)];
    accS = __builtin_amdgcn_mfma_f32_32x32x16_bf16(af, bf, accS, 0, 0, 0);
  }
#pragma unroll
  for (int r = 0; r < 16; ++r) {
    int iloc = (r & 3) + 8 * (r >> 2) + 4 * half;
    int ii = 32 * wr + iloc;
    int jj = 32 * wc + col;
    float m = (jj <= ii) ? accS[r] : 0.f;
    sS[swi(ii, jj)] = bfr(m);
  }
  __syncthreads();
  f32x16 acc;
#pragma unroll
  for (int r = 0; r < 16; ++r) acc[r] = 0.f;
#pragma unroll
  for (int kk = 0; kk < 4; ++kk) {
    int j0 = kk * 16 + half * 8;
    bf16x8 af = *(const bf16x8*)&sS[swi(arow, j0)];
    bf16x8 bf = *(const bf16x8*)&vT[swi(bcol, j0)];
    acc = __builtin_amdgcn_mfma_f32_32x32x16_bf16(af, bf, acc, 0, 0, 0);
  }
#pragma unroll
  for (int kk = 0; kk < 4; ++kk) {
    int aa = kk * 16 + half * 8;
    bf16x8 af = *(const bf16x8*)&qb[swi(arow, aa)];
    bf16x8 bf = *(const bf16x8*)&dT[swi(bcol, aa)];
    acc = __builtin_amdgcn_mfma_f32_32x32x16_bf16(af, bf, acc, 0, 0, 0);
  }
  float* ob = outg + (size_t)rowb * DV_;
#pragma unroll
  for (int r = 0; r < 16; ++r) {
    int iloc = (r & 3) + 8 * (r >> 2) + 4 * half;
    int ii = 32 * wr + iloc;
    int cc = 32 * wc + col;
    ob[(size_t)ii * DV_ + cc] = acc[r] * Pf[ii];
  }
}

// ---------------------------------------------------------------------------
extern "C" void kernel_launch(void* const* d_in, const int* in_sizes, int n_in,
                              void* d_out, int out_size, void* d_ws, size_t ws_size,
                              hipStream_t stream) {
  const float* q = (const float*)d_in[0];
  const float* k = (const float*)d_in[1];
  const float* v = (const float*)d_in[2];
  const float* om = (const float*)d_in[3];
  float* out = (float*)d_out;

  float* ws = (float*)d_ws;
  float* qc = ws;                          // BH_*N_       = 32768
  float* kc = qc + BH_ * N_;               // BH_*N_       = 32768
  float* ksum = kc + BH_ * N_;             // NCH_*DK_     = 32768
  float* kv = ksum + (size_t)NCH_ * DK_;   // NCH_*DK_*DV_ = 2,097,152

  front_kernel<<<NCH_ + BH_ * N_ / 4, 256, 0, stream>>>(k, v, om, qc, kc,
                                                        ksum, kv);
  out_mfma_kernel<<<NCH_, 256, 0, stream>>>(q, k, v, qc, kc, ksum, kv, out);
}

// Round 12
// 68.312 us; speedup vs baseline: 1.1588x; 1.1588x over previous
//
#include <hip/hip_runtime.h>
#include <cmath>

constexpr int B_ = 2, H_ = 8, N_ = 2048, DK_ = 64, DV_ = 64;
constexpr int BH_ = B_ * H_;      // 16
constexpr int C_ = 64;            // chunk size
constexpr int NC_ = N_ / C_;      // 32 chunks per (b,h)
constexpr int NCH_ = BH_ * NC_;   // 512 chunks total

using f32x16 = __attribute__((ext_vector_type(16))) float;
using bf16x8 = __attribute__((ext_vector_type(8))) __bf16;

// float -> bf16 bits, round-to-nearest-even
__device__ inline unsigned short bfr(float x) {
  unsigned u = __float_as_uint(x);
  return (unsigned short)((u + 0x7FFFu + ((u >> 16) & 1u)) >> 16);
}
__device__ inline unsigned pk2(float lo, float hi) {
  return (unsigned)bfr(lo) | ((unsigned)bfr(hi) << 16);
}
// swizzled ushort index into a [64][64] bf16 tile (row stride 128B),
// byte ^= (row&7)<<4 — spreads fixed-column fragment reads across banks.
__device__ inline int swi(int row, int a) {
  return (row * 128 + (((a * 2) ^ ((row & 7) << 4)))) >> 1;
}

// ---------------------------------------------------------------------------
// Kernel 1: per-row coefficients (round-1 proven shape).
// ---------------------------------------------------------------------------
__global__ __launch_bounds__(256) void coef_kernel(const float* __restrict__ om,
                                                   float* __restrict__ qc,
                                                   float* __restrict__ kc) {
  int row = blockIdx.x * 4 + (threadIdx.x >> 6);
  int lane = threadIdx.x & 63;
  const float* r = om + (size_t)row * N_;
  float s = 0.f;
#pragma unroll
  for (int kk = 0; kk < N_ / 256; ++kk) {
    float4 v4 = *(const float4*)(r + kk * 256 + lane * 4);
    s += (v4.x + v4.y) + (v4.z + v4.w);
  }
#pragma unroll
  for (int off = 32; off > 0; off >>= 1) s += __shfl_xor(s, off, 64);
  if (lane == 0) {
    float o0 = r[0];
    qc[row] = o0 / sqrtf(s);
    kc[row] = 1.0f / o0;
  }
}

// ---------------------------------------------------------------------------
// Kernel 2: per-chunk sums (round-1 proven version).
// ---------------------------------------------------------------------------
__global__ __launch_bounds__(256) void chunksum_kernel(const float* __restrict__ kg,
                                                       const float* __restrict__ vg,
                                                       const float* __restrict__ kc,
                                                       float* __restrict__ ksum,
                                                       float* __restrict__ kvsum) {
  __shared__ float kb[C_][DK_];
  __shared__ float vs[C_][DV_];
  int chunk = blockIdx.x;
  int bh = chunk / NC_, ci = chunk - bh * NC_;
  int r0 = ci * C_;
  size_t gbase = ((size_t)bh * N_ + r0) * DK_;
  int t = threadIdx.x;
#pragma unroll
  for (int p = 0; p < 4; ++p) {
    int f = t + p * 256;
    int row = f >> 4, col = (f & 15) * 4;
    float sc = kc[bh * N_ + r0 + row];
    float4 k4 = *(const float4*)(kg + gbase + (size_t)f * 4);
    k4.x *= sc; k4.y *= sc; k4.z *= sc; k4.w *= sc;
    *(float4*)&kb[row][col] = k4;
    *(float4*)&vs[row][col] = *(const float4*)(vg + gbase + (size_t)f * 4);
  }
  __syncthreads();
  int dk0 = (t & 15) * 4, dv0 = (t >> 4) * 4;
  float acc[4][4] = {};
  float ks[4] = {};
  for (int r = 0; r < C_; ++r) {
    float4 k4 = *(const float4*)&kb[r][dk0];
    float4 v4 = *(const float4*)&vs[r][dv0];
    float ka[4] = {k4.x, k4.y, k4.z, k4.w};
    float va[4] = {v4.x, v4.y, v4.z, v4.w};
#pragma unroll
    for (int i = 0; i < 4; ++i) {
      ks[i] += ka[i];
#pragma unroll
      for (int j = 0; j < 4; ++j) acc[i][j] += ka[i] * va[j];
    }
  }
  float* kvc = kvsum + (size_t)chunk * (DK_ * DV_);
#pragma unroll
  for (int i = 0; i < 4; ++i)
    *(float4*)(kvc + (size_t)(dk0 + i) * DV_ + dv0) =
        make_float4(acc[i][0], acc[i][1], acc[i][2], acc[i][3]);
  if (t < 16) {
#pragma unroll
    for (int i = 0; i < 4; ++i) ksum[(size_t)chunk * DK_ + dk0 + i] = ks[i];
  }
}

// ---------------------------------------------------------------------------
// Kernel 3: exclusive prefix over chunks (round-1 in-place version).
// ---------------------------------------------------------------------------
__global__ __launch_bounds__(256) void scan_kernel(float* __restrict__ ksum,
                                                   float* __restrict__ kvsum) {
  constexpr int PER = DK_ * DV_ + DK_;   // 4160 elements per bh
  int idx = blockIdx.x * 256 + threadIdx.x;
  if (idx >= BH_ * PER) return;
  int bh = idx / PER, e = idx - bh * PER;
  float run = 0.f;
  if (e < DK_ * DV_) {
    float* p = kvsum + (size_t)bh * NC_ * (DK_ * DV_) + e;
    for (int ci = 0; ci < NC_; ++ci) {
      float tv = p[(size_t)ci * (DK_ * DV_)];
      p[(size_t)ci * (DK_ * DV_)] = run;
      run += tv;
    }
  } else {
    float* p = ksum + (size_t)bh * NC_ * DK_ + (e - DK_ * DV_);
    for (int ci = 0; ci < NC_; ++ci) {
      float tv = p[(size_t)ci * DK_];
      p[(size_t)ci * DK_] = run;
      run += tv;
    }
  }
}

// ---------------------------------------------------------------------------
// Kernel 4 (MFMA numerator + f32 P):
//   S = Q̄·K̄ᵀ (causal, bf16 MFMA), O_num = S·V + Q̄·D_pre (bf16 MFMA),
//   P[i] = q̄_i·(T_pre + cumsum_chunk(k̄)[i])  — FULL f32 (no bf16 anywhere),
//   out = O_num / max(|P|,1).
// P in f32 is essential: P is a cancelling sum; bf16-rounded inputs gave
// ~28% output error in round 6. The numerator only needs relative accuracy.
// ---------------------------------------------------------------------------
__global__ __launch_bounds__(256) void out_mfma_kernel(
    const float* __restrict__ qg, const float* __restrict__ kg,
    const float* __restrict__ vg, const float* __restrict__ qc,
    const float* __restrict__ kc, const float* __restrict__ ksum,
    const float* __restrict__ kvsum, float* __restrict__ outg) {
  __shared__ unsigned short qb[64 * 64];   // q̄[i][a]  bf16, swizzled
  __shared__ unsigned short kb[64 * 64];   // k̄[j][a]  bf16, swizzled
  __shared__ unsigned short sS[64 * 64];   // S[i][j]  bf16, swizzled
  __shared__ unsigned short vT[64 * 64];   // V^T[c][j] bf16, swizzled
  __shared__ unsigned short dT[64 * 64];   // D^T[c][a] bf16, swizzled
  __shared__ float Tc[2][64][68];          // f32 in-chunk cumsum of k̄ (+4 pad)
  __shared__ float Tl[64];                 // f32 T_pre
  __shared__ float Pf[64];                 // 1/P

  const int chunk = blockIdx.x;
  const int bh = chunk >> 5, ci = chunk & 31;
  const int r0 = ci * C_;
  const int rowb = bh * N_ + r0;
  const size_t gbase = (size_t)rowb * DK_;
  const int t = threadIdx.x;
  const int i = t >> 2, a0 = (t & 3) * 16;

  // ---- staging ----
  float xq[16];
  {
    float qcv = qc[rowb + i];
    float kcv = kc[rowb + i];
    float xk[16], xv[16], xd[16];
    {
      const float* qp = qg + gbase + (size_t)i * 64 + a0;
      const float* kp = kg + gbase + (size_t)i * 64 + a0;
      const float* vp = vg + gbase + (size_t)i * 64 + a0;
      const float* dp = kvsum + (size_t)chunk * (DK_ * DV_) + (size_t)i * 64 + a0;
#pragma unroll
      for (int u = 0; u < 4; ++u) {
        *(float4*)&xq[u * 4] = *(const float4*)(qp + u * 4);
        *(float4*)&xk[u * 4] = *(const float4*)(kp + u * 4);
        *(float4*)&xv[u * 4] = *(const float4*)(vp + u * 4);
        *(float4*)&xd[u * 4] = *(const float4*)(dp + u * 4);
      }
    }
#pragma unroll
    for (int u = 0; u < 16; ++u) { xq[u] *= qcv; xk[u] *= kcv; }
    // f32 k̄ seeds the in-chunk cumsum
#pragma unroll
    for (int u4 = 0; u4 < 4; ++u4)
      *(float4*)&Tc[0][i][a0 + u4 * 4] = *(const float4*)&xk[u4 * 4];
    unsigned* qbu = (unsigned*)qb;
    unsigned* kbu = (unsigned*)kb;
#pragma unroll
    for (int u = 0; u < 8; ++u) {
      int a = a0 + 2 * u;
      int bi = (i * 128 + (((a * 2) ^ ((i & 7) << 4)))) >> 2;
      qbu[bi] = pk2(xq[2 * u], xq[2 * u + 1]);
      kbu[bi] = pk2(xk[2 * u], xk[2 * u + 1]);
    }
#pragma unroll
    for (int u = 0; u < 16; ++u) {
      int c = a0 + u;
      vT[swi(c, i)] = bfr(xv[u]);           // V^T[c][j=i]
      dT[swi(c, i)] = bfr(xd[u]);           // D^T[c][a=i]
    }
    if (t < 64) Tl[t] = ksum[(size_t)chunk * DK_ + t];
  }
  __syncthreads();

  // ---- f32 in-chunk inclusive cumsum of k̄ over rows (Hillis-Steele) ----
  {
    int p = 0;
#pragma unroll
    for (int step = 1; step < 64; step <<= 1) {
      float4 cur[4], prv[4];
#pragma unroll
      for (int u4 = 0; u4 < 4; ++u4) {
        cur[u4] = *(const float4*)&Tc[p][i][a0 + u4 * 4];
        if (i >= step)
          prv[u4] = *(const float4*)&Tc[p][i - step][a0 + u4 * 4];
        else
          prv[u4] = make_float4(0.f, 0.f, 0.f, 0.f);
      }
#pragma unroll
      for (int u4 = 0; u4 < 4; ++u4) {
        float4 w = make_float4(cur[u4].x + prv[u4].x, cur[u4].y + prv[u4].y,
                               cur[u4].z + prv[u4].z, cur[u4].w + prv[u4].w);
        *(float4*)&Tc[p ^ 1][i][a0 + u4 * 4] = w;
      }
      __syncthreads();
      p ^= 1;
    }
    // result in Tc[0]
  }

  // ---- P[i] = q̄_i·(T_pre + Tc[i])  (all f32) ----
  {
    float part = 0.f;
#pragma unroll
    for (int u = 0; u < 16; ++u)
      part += xq[u] * (Tl[a0 + u] + Tc[0][i][a0 + u]);
    part += __shfl_xor(part, 1, 64);
    part += __shfl_xor(part, 2, 64);
    if ((t & 3) == 0) Pf[i] = 1.0f / fmaxf(fabsf(part), 1.0f);
  }

  const int lane = t & 63, w = t >> 6;
  const int wr = w >> 1, wc = w & 1;
  const int half = lane >> 5, col = lane & 31;
  const int arow = 32 * wr + col;           // A-fragment row for this lane
  const int bcol = 32 * wc + col;           // B-fragment col for this lane

  // ---- M1: S = Q̄ K̄ᵀ ----
  f32x16 accS;
#pragma unroll
  for (int r = 0; r < 16; ++r) accS[r] = 0.f;
#pragma unroll
  for (int kk = 0; kk < 4; ++kk) {
    int aa = kk * 16 + half * 8;
    bf16x8 af = *(const bf16x8*)&qb[swi(arow, aa)];
    bf16x8 bf = *(const bf16x8*)&kb[swi(bcol, aa)];
    accS = __builtin_amdgcn_mfma_f32_32x32x16_bf16(af, bf, accS, 0, 0, 0);
  }
  // causal mask, write S (bf16)
#pragma unroll
  for (int r = 0; r < 16; ++r) {
    int iloc = (r & 3) + 8 * (r >> 2) + 4 * half;
    int ii = 32 * wr + iloc;
    int jj = 32 * wc + col;
    float m = (jj <= ii) ? accS[r] : 0.f;
    sS[swi(ii, jj)] = bfr(m);
  }
  __syncthreads();   // sS + Pf visible

  // ---- M2+M3: O = S·V + Q̄·D ----
  f32x16 acc;
#pragma unroll
  for (int r = 0; r < 16; ++r) acc[r] = 0.f;
#pragma unroll
  for (int kk = 0; kk < 4; ++kk) {
    int j0 = kk * 16 + half * 8;
    bf16x8 af = *(const bf16x8*)&sS[swi(arow, j0)];
    bf16x8 bf = *(const bf16x8*)&vT[swi(bcol, j0)];
    acc = __builtin_amdgcn_mfma_f32_32x32x16_bf16(af, bf, acc, 0, 0, 0);
  }
#pragma unroll
  for (int kk = 0; kk < 4; ++kk) {
    int aa = kk * 16 + half * 8;
    bf16x8 af = *(const bf16x8*)&qb[swi(arow, aa)];
    bf16x8 bf = *(const bf16x8*)&dT[swi(bcol, aa)];
    acc = __builtin_amdgcn_mfma_f32_32x32x16_bf16(af, bf, acc, 0, 0, 0);
  }

  // ---- epilogue ----
  float* ob = outg + (size_t)rowb * DV_;
#pragma unroll
  for (int r = 0; r < 16; ++r) {
    int iloc = (r & 3) + 8 * (r >> 2) + 4 * half;
    int ii = 32 * wr + iloc;
    int cc = 32 * wc + col;
    ob[(size_t)ii * DV_ + cc] = acc[r] * Pf[ii];
  }
}

// ---------------------------------------------------------------------------
extern "C" void kernel_launch(void* const* d_in, const int* in_sizes, int n_in,
                              void* d_out, int out_size, void* d_ws, size_t ws_size,
                              hipStream_t stream) {
  const float* q = (const float*)d_in[0];
  const float* k = (const float*)d_in[1];
  const float* v = (const float*)d_in[2];
  const float* om = (const float*)d_in[3];
  float* out = (float*)d_out;

  float* ws = (float*)d_ws;
  float* qc = ws;                          // BH_*N_      = 32768
  float* kc = qc + BH_ * N_;               // BH_*N_      = 32768
  float* ksum = kc + BH_ * N_;             // NCH_*DK_    = 32768
  float* kv = ksum + (size_t)NCH_ * DK_;   // NCH_*DK_*DV_ = 2,097,152

  coef_kernel<<<BH_ * N_ / 4, 256, 0, stream>>>(om, qc, kc);
  chunksum_kernel<<<NCH_, 256, 0, stream>>>(k, v, kc, ksum, kv);
  constexpr int SCAN_TOTAL = BH_ * (DK_ * DV_ + DK_);
  scan_kernel<<<(SCAN_TOTAL + 255) / 256, 256, 0, stream>>>(ksum, kv);
  out_mfma_kernel<<<NCH_, 256, 0, stream>>>(q, k, v, qc, kc, ksum, kv, out);
}